// Round 2
// baseline (393.307 us; speedup 1.0000x reference)
//
#include <hip/hip_runtime.h>
#include <hip/hip_bf16.h>

#define NNODES 100000
#define NEDGES 1600000
#define IND 128
#define HD 64
#define OUTD 2
#define NG 64
#define BINSHIFT 9
#define BINSZ 512            // nodes per bin
#define BSTRIDE 12288        // edge slots per bin (padded CSR rows fit: mean+28sigma)
#define PB 256               // partition blocks

typedef __attribute__((ext_vector_type(8))) short short8v;
typedef __attribute__((ext_vector_type(4))) float floatx4;

static __device__ __forceinline__ unsigned short f2bf(float f) {
    __hip_bfloat16 h = __float2bfloat16(f);
    return *(unsigned short*)&h;
}
static __device__ __forceinline__ float bf2f(unsigned short u) {
    __hip_bfloat16 h = *(__hip_bfloat16*)&u;
    return __bfloat162float(h);
}

// unpack 4 bf16 feats from uint2 and accumulate (bf16->f32 = shift, exact)
static __device__ __forceinline__ void unpack_add(uint2 u, float& a0, float& a1,
                                                  float& a2, float& a3) {
    a0 += __uint_as_float(u.x << 16);
    a1 += __uint_as_float(u.x & 0xffff0000u);
    a2 += __uint_as_float(u.y << 16);
    a3 += __uint_as_float(u.y & 0xffff0000u);
}

// ============ single-pass binned edge partition (1024 thr: 16 waves/CU) ====
// dst cached in registers between histogram and partition passes (read once).
__global__ __launch_bounds__(1024) void binP_kernel(const int* __restrict__ src,
                                                    const int* __restrict__ dst,
                                                    int* __restrict__ binCount,
                                                    unsigned int* __restrict__ binned,
                                                    int E, int nbins) {
    __shared__ int lh[256];
    __shared__ int lbase[256];
    int t = threadIdx.x;
    if (t < 256) lh[t] = 0;
    __syncthreads();
    int ebpb = (E + PB - 1) / PB;
    int e0 = blockIdx.x * ebpb;
    int e1 = min(e0 + ebpb, E);
    int dcache[8];                       // ceil(6250/1024) = 7
    int ec = 0;
    for (int e = e0 + t; e < e1; e += 1024) {
        int d = dst[e];
        dcache[ec++] = d;
        atomicAdd(&lh[d >> BINSHIFT], 1);
    }
    __syncthreads();
    if (t < nbins) {
        int c = lh[t];
        if (c > 0) lbase[t] = atomicAdd(&binCount[t], c);
        lh[t] = 0;                       // reuse as local cursor
    }
    __syncthreads();
    ec = 0;
    for (int e = e0 + t; e < e1; e += 1024) {
        int d = dcache[ec++];
        int b = d >> BINSHIFT;
        int idx = atomicAdd(&lh[b], 1);
        binned[(size_t)b * BSTRIDE + lbase[b] + idx] =
            ((unsigned int)(d & (BINSZ - 1)) << 17) | (unsigned int)src[e];
    }
}

// HD (1024 thr): one block per bin. histogram -> dinv -> LDS exclusive scan
// of PADDED degrees (rows 16B-aligned for uint4 ssrc batch loads) ->
// packed rowinfo = (start<<10)|deg -> CSR scatter with LDS countdown.
__global__ __launch_bounds__(1024) void binHD_kernel(const unsigned int* __restrict__ binned,
                                                     const int* __restrict__ binCount,
                                                     float* __restrict__ dinv,
                                                     unsigned int* __restrict__ rowinfo,
                                                     int* __restrict__ ssrc, int n) {
    __shared__ int dh[BINSZ];
    __shared__ int rp[BINSZ];
    __shared__ int wsum[4];
    int b = blockIdx.x, t = threadIdx.x;
    int lane = t & 63, wv = t >> 6;
    if (t < BINSZ) dh[t] = 0;
    __syncthreads();
    int s0 = b * BSTRIDE;
    int cnt = binCount[b];
    for (int i = t; i < cnt; i += 1024)
        atomicAdd(&dh[binned[s0 + i] >> 17], 1);
    __syncthreads();
    // dinv (deg + self loop)
    if (t < BINSZ) {
        int node = (b << BINSHIFT) + t;
        if (node < n) dinv[node] = 1.0f / sqrtf((float)(dh[t] + 1));
    }
    // exclusive scan of padded degs (round up to 4) by threads 0..255;
    // all threads participate in barriers
    int d0 = 0, d1 = 0, p = 0;
    if (t < 256) {
        d0 = (dh[2 * t] + 3) & ~3;
        d1 = (dh[2 * t + 1] + 3) & ~3;
        p = d0 + d1;
    }
    int sc = p;
#pragma unroll
    for (int d = 1; d < 64; d <<= 1) { int v = __shfl_up(sc, d, 64); if (lane >= d) sc += v; }
    if (t < 256 && lane == 63) wsum[wv] = sc;
    __syncthreads();
    if (t < 256) {
        int add = 0;
        for (int w2 = 0; w2 < wv; w2++) add += wsum[w2];
        int ex = sc - p + add;
        rp[2 * t]     = ex;
        rp[2 * t + 1] = ex + d0;
    }
    __syncthreads();
    // packed rowinfo (aligned start, REAL deg)
    if (t < BINSZ) {
        int node = (b << BINSHIFT) + t;
        if (node < n)
            rowinfo[node] = ((unsigned int)(s0 + rp[t]) << 10) |
                            (unsigned int)min(dh[t], 1023);
    }
    __syncthreads();
    // scatter (dh consumed as countdown)
    for (int i = t; i < cnt; i += 1024) {
        unsigned int rec = binned[s0 + i];
        int doff = rec >> 17;
        int s = rec & 0x1FFFF;
        int idx = atomicSub(&dh[doff], 1) - 1;
        ssrc[s0 + rp[doff] + idx] = s;
    }
}

// ---------------- prep: 3 W transposes + gcnt batch histogram --------------
__global__ __launch_bounds__(256) void prep_kernel(const float* __restrict__ W1,
                                                   const float* __restrict__ W2,
                                                   const float* __restrict__ W3,
                                                   unsigned short* __restrict__ WT1,
                                                   unsigned short* __restrict__ WT2,
                                                   unsigned short* __restrict__ WT3,
                                                   const int* __restrict__ batch,
                                                   float* __restrict__ gcnt, int n) {
    int blk = blockIdx.x;
    if (blk < 64) {
        int i = blk * 256 + threadIdx.x;
        if (i < 64 * IND) {
            int nn2 = i / IND, k = i - nn2 * IND;
            WT1[i] = f2bf(W1[k * 64 + nn2]);
        } else if (i < 64 * IND + 64 * HD) {
            int j = i - 64 * IND;
            int nn2 = j / HD, k = j - nn2 * HD;
            WT2[j] = f2bf(W2[k * 64 + nn2]);
        } else {
            int j = i - 64 * IND - 64 * HD;
            int nn2 = j / HD, k = j - nn2 * HD;
            WT3[j] = f2bf(W3[k * 64 + nn2]);
        }
    } else {
        __shared__ float lg[NG];
        int t = threadIdx.x;
        if (t < NG) lg[t] = 0.f;
        __syncthreads();
        int nb2 = gridDim.x - 64;
        int per = (n + nb2 - 1) / nb2;
        int i0 = (blk - 64) * per;
        int i1 = min(i0 + per, n);
        for (int i = i0 + t; i < i1; i += 256)
            atomicAdd(&lg[batch[i]], 1.f);
        __syncthreads();
        if (t < NG) atomicAdd(&gcnt[t], lg[t]);
    }
}

// ---------------- MFMA matmul: Tb[n][:] = bf16( dinv[n] * (X[n,:K] @ W) ) --
// B-rows remapped so each lane's 4 outputs are CONTIGUOUS features
// (4*col .. 4*col+3) -> one uint2 (4x bf16) store per node-row per lane.
template <int K, bool BF16IN>
__global__ __launch_bounds__(256) void mm_mfma_kernel(const void* __restrict__ Xv,
                                                      const unsigned short* __restrict__ WT,
                                                      const float* __restrict__ dinv,
                                                      unsigned short* __restrict__ Tb, int nn) {
    const int lane = threadIdx.x & 63;
    const int wv   = threadIdx.x >> 6;
    const int nb   = blockIdx.x * 64 + wv * 16;
    if (nb >= nn) return;
    const int col  = lane & 15;
    const int quad = lane >> 4;
    const int m    = min(nb + col, nn - 1);

    floatx4 acc0 = {0.f, 0.f, 0.f, 0.f};
    floatx4 acc1 = {0.f, 0.f, 0.f, 0.f};
    floatx4 acc2 = {0.f, 0.f, 0.f, 0.f};
    floatx4 acc3 = {0.f, 0.f, 0.f, 0.f};

#pragma unroll
    for (int ks = 0; ks < K; ks += 32) {
        const int k0 = ks + quad * 8;
        short8v a;
        if (BF16IN) {
            a = *(const short8v*)((const unsigned short*)Xv + (size_t)m * K + k0);
        } else {
            const float* xr = (const float*)Xv + (size_t)m * K + k0;
            float4 f0 = *(const float4*)(xr);
            float4 f1 = *(const float4*)(xr + 4);
            a[0] = (short)f2bf(f0.x); a[1] = (short)f2bf(f0.y);
            a[2] = (short)f2bf(f0.z); a[3] = (short)f2bf(f0.w);
            a[4] = (short)f2bf(f1.x); a[5] = (short)f2bf(f1.y);
            a[6] = (short)f2bf(f1.z); a[7] = (short)f2bf(f1.w);
        }
        // feature rows 4*col+0..3 (contiguous per lane in output)
        short8v b0 = *(const short8v*)(WT + (size_t)(4 * col + 0) * K + k0);
        short8v b1 = *(const short8v*)(WT + (size_t)(4 * col + 1) * K + k0);
        short8v b2 = *(const short8v*)(WT + (size_t)(4 * col + 2) * K + k0);
        short8v b3 = *(const short8v*)(WT + (size_t)(4 * col + 3) * K + k0);
        acc0 = __builtin_amdgcn_mfma_f32_16x16x32_bf16(a, b0, acc0, 0, 0, 0);
        acc1 = __builtin_amdgcn_mfma_f32_16x16x32_bf16(a, b1, acc1, 0, 0, 0);
        acc2 = __builtin_amdgcn_mfma_f32_16x16x32_bf16(a, b2, acc2, 0, 0, 0);
        acc3 = __builtin_amdgcn_mfma_f32_16x16x32_bf16(a, b3, acc3, 0, 0, 0);
    }

#pragma unroll
    for (int r = 0; r < 4; r++) {
        int node = nb + quad * 4 + r;
        if (node < nn) {
            float sc = dinv[node];
            unsigned int lo = (unsigned int)f2bf(sc * acc0[r]) |
                              ((unsigned int)f2bf(sc * acc1[r]) << 16);
            unsigned int hi = (unsigned int)f2bf(sc * acc2[r]) |
                              ((unsigned int)f2bf(sc * acc3[r]) << 16);
            uint2 st; st.x = lo; st.y = hi;
            ((uint2*)Tb)[(size_t)node * 16 + col] = st;
        }
    }
}

// ---------------- pull aggregation, 2 nodes/wave, wide gathers -------------
// Lane = (g,q): g = edge subgroup 0..3, q = feature quad (feats 4q..4q+3).
// Per 16-edge batch: 1 uint4 ssrc load (4 edges per group) + 4 uint2 row
// gathers. ssrc for batch k+1 prefetched during batch k's gathers. Two
// nodes interleaved per wave -> 2 independent miss streams.
__global__ __launch_bounds__(256) void agg_kernel(const unsigned short* __restrict__ Tb,
                                                  const unsigned int* __restrict__ rowinfo,
                                                  const int* __restrict__ ssrc,
                                                  const float* __restrict__ dinv,
                                                  const float* __restrict__ bias,
                                                  unsigned short* __restrict__ Ob, int nn) {
    int wave = __builtin_amdgcn_readfirstlane((blockIdx.x * 256 + threadIdx.x) >> 6);
    int lane = threadIdx.x & 63;
    int g = lane >> 4;           // edge subgroup 0..3
    int q = lane & 15;           // feature quad
    int nA = wave * 2;
    if (nA >= nn) return;
    int nB = nA + 1;
    bool hasB = (nB < nn);
    const uint2* T64 = (const uint2*)Tb;

    float aA0 = 0.f, aA1 = 0.f, aA2 = 0.f, aA3 = 0.f;
    float aB0 = 0.f, aB1 = 0.f, aB2 = 0.f, aB3 = 0.f;

    // self loops (pre-scaled rows), counted once via group 0
    if (g == 0) {
        uint2 u = T64[(size_t)nA * 16 + q];
        unpack_add(u, aA0, aA1, aA2, aA3);
        if (hasB) {
            uint2 v = T64[(size_t)nB * 16 + q];
            unpack_add(v, aB0, aB1, aB2, aB3);
        }
    }

    unsigned int infoA = rowinfo[nA];
    unsigned int infoB = hasB ? rowinfo[nB] : 0u;
    int iA = (int)(infoA >> 10), reA = iA + (int)(infoA & 1023);
    int iB = (int)(infoB >> 10), reB = iB + (int)(infoB & 1023);

    // ---- 16-edge batches, interleaved, one-batch-ahead ssrc prefetch ----
    uint4 sA, sB;
    bool pA = (iA + 16 <= reA);
    bool pB = (iB + 16 <= reB);
    if (pA) sA = *(const uint4*)(ssrc + iA + 4 * g);   // rows 16B-aligned
    if (pB) sB = *(const uint4*)(ssrc + iB + 4 * g);
    while (pA || pB) {
        uint2 uA0, uA1, uA2, uA3, uB0, uB1, uB2, uB3;
        if (pA) {
            uA0 = T64[(size_t)sA.x * 16 + q];
            uA1 = T64[(size_t)sA.y * 16 + q];
            uA2 = T64[(size_t)sA.z * 16 + q];
            uA3 = T64[(size_t)sA.w * 16 + q];
        }
        if (pB) {
            uB0 = T64[(size_t)sB.x * 16 + q];
            uB1 = T64[(size_t)sB.y * 16 + q];
            uB2 = T64[(size_t)sB.z * 16 + q];
            uB3 = T64[(size_t)sB.w * 16 + q];
        }
        bool npA = pA && (iA + 32 <= reA);
        bool npB = pB && (iB + 32 <= reB);
        uint4 nsA, nsB;
        if (npA) nsA = *(const uint4*)(ssrc + iA + 16 + 4 * g);
        if (npB) nsB = *(const uint4*)(ssrc + iB + 16 + 4 * g);
        if (pA) {
            unpack_add(uA0, aA0, aA1, aA2, aA3);
            unpack_add(uA1, aA0, aA1, aA2, aA3);
            unpack_add(uA2, aA0, aA1, aA2, aA3);
            unpack_add(uA3, aA0, aA1, aA2, aA3);
            iA += 16;
        }
        if (pB) {
            unpack_add(uB0, aB0, aB1, aB2, aB3);
            unpack_add(uB1, aB0, aB1, aB2, aB3);
            unpack_add(uB2, aB0, aB1, aB2, aB3);
            unpack_add(uB3, aB0, aB1, aB2, aB3);
            iB += 16;
        }
        sA = nsA; sB = nsB;
        pA = npA; pB = npB;
    }

    // ---- tails (<16 edges each), interleaved, group g takes every 4th ----
    int eA = iA + g, eB = iB + g;
    while (eA < reA || eB < reB) {
        int sa, sb;
        uint2 ua, ub;
        if (eA < reA) sa = ssrc[eA];
        if (eB < reB) sb = ssrc[eB];
        if (eA < reA) ua = T64[(size_t)sa * 16 + q];
        if (eB < reB) ub = T64[(size_t)sb * 16 + q];
        if (eA < reA) { unpack_add(ua, aA0, aA1, aA2, aA3); eA += 4; }
        if (eB < reB) { unpack_add(ub, aB0, aB1, aB2, aB3); eB += 4; }
    }

    // combine the 4 edge-groups (butterfly over lane bits 4,5)
    aA0 += __shfl_xor(aA0, 16, 64); aA0 += __shfl_xor(aA0, 32, 64);
    aA1 += __shfl_xor(aA1, 16, 64); aA1 += __shfl_xor(aA1, 32, 64);
    aA2 += __shfl_xor(aA2, 16, 64); aA2 += __shfl_xor(aA2, 32, 64);
    aA3 += __shfl_xor(aA3, 16, 64); aA3 += __shfl_xor(aA3, 32, 64);
    aB0 += __shfl_xor(aB0, 16, 64); aB0 += __shfl_xor(aB0, 32, 64);
    aB1 += __shfl_xor(aB1, 16, 64); aB1 += __shfl_xor(aB1, 32, 64);
    aB2 += __shfl_xor(aB2, 16, 64); aB2 += __shfl_xor(aB2, 32, 64);
    aB3 += __shfl_xor(aB3, 16, 64); aB3 += __shfl_xor(aB3, 32, 64);

    if (g == 0) {
        float4 bv = *(const float4*)(bias + 4 * q);
        float scA = dinv[nA];
        float o0 = scA * aA0 + bv.x;
        float o1 = scA * aA1 + bv.y;
        float o2 = scA * aA2 + bv.z;
        float o3 = scA * aA3 + bv.w;
        o0 = o0 > 0.f ? o0 : 0.f;
        o1 = o1 > 0.f ? o1 : 0.f;
        o2 = o2 > 0.f ? o2 : 0.f;
        o3 = o3 > 0.f ? o3 : 0.f;
        uint2 st;
        st.x = (unsigned int)f2bf(o0) | ((unsigned int)f2bf(o1) << 16);
        st.y = (unsigned int)f2bf(o2) | ((unsigned int)f2bf(o3) << 16);
        ((uint2*)Ob)[(size_t)nA * 16 + q] = st;
        if (hasB) {
            float scB = dinv[nB];
            float p0 = scB * aB0 + bv.x;
            float p1 = scB * aB1 + bv.y;
            float p2 = scB * aB2 + bv.z;
            float p3 = scB * aB3 + bv.w;
            p0 = p0 > 0.f ? p0 : 0.f;
            p1 = p1 > 0.f ? p1 : 0.f;
            p2 = p2 > 0.f ? p2 : 0.f;
            p3 = p3 > 0.f ? p3 : 0.f;
            uint2 sq;
            sq.x = (unsigned int)f2bf(p0) | ((unsigned int)f2bf(p1) << 16);
            sq.y = (unsigned int)f2bf(p2) | ((unsigned int)f2bf(p3) << 16);
            ((uint2*)Ob)[(size_t)nB * 16 + q] = sq;
        }
    }
}

// ---------------- mean pool (bf16 input): sorted-run register accumulation -
__global__ __launch_bounds__(256) void pool_kernel(const unsigned short* __restrict__ Hb,
                                                   const int* __restrict__ batch,
                                                   float* __restrict__ pooled, int nn) {
    int wid = (blockIdx.x * 256 + threadIdx.x) >> 6;
    int lane = threadIdx.x & 63;
    int nwaves = (gridDim.x * 256) >> 6;
    int per = (nn + nwaves - 1) / nwaves;
    int n0 = wid * per;
    int n1 = n0 + per; if (n1 > nn) n1 = nn;
    if (n0 >= n1) return;
    int cur = batch[n0];
    float acc = 0.f;
    for (int n = n0; n < n1; ++n) {
        int g = batch[n];
        if (g != cur) {
            atomicAdd(&pooled[cur * 64 + lane], acc);
            acc = 0.f; cur = g;
        }
        acc += bf2f(Hb[(size_t)n * 64 + lane]);
    }
    atomicAdd(&pooled[cur * 64 + lane], acc);
}

// ---------------- MLP head (single block) ----------------
__global__ __launch_bounds__(256) void head_kernel(const float* __restrict__ pooled,
                                                   const float* __restrict__ gcnt,
                                                   const float* __restrict__ Wm1,
                                                   const float* __restrict__ bm1,
                                                   const float* __restrict__ Wm2,
                                                   const float* __restrict__ bm2,
                                                   float* __restrict__ out) {
    __shared__ float P[NG * 64];
    __shared__ float Z[NG * 64];
    int tid = threadIdx.x;
    for (int i = tid; i < NG * 64; i += 256) {
        int g = i >> 6;
        float c = gcnt[g];
        c = c > 1.f ? c : 1.f;
        P[i] = pooled[i] / c;
    }
    __syncthreads();
    for (int i = tid; i < NG * 64; i += 256) {
        int g = i >> 6, j = i & 63;
        float a = bm1[j];
#pragma unroll 8
        for (int k = 0; k < 64; ++k) a += P[g * 64 + k] * Wm1[k * 64 + j];
        Z[i] = a > 0.f ? a : 0.f;
    }
    __syncthreads();
    for (int i = tid; i < NG * OUTD; i += 256) {
        int g = i / OUTD, o = i % OUTD;
        float a = bm2[o];
#pragma unroll 8
        for (int k = 0; k < 64; ++k) a += Z[g * 64 + k] * Wm2[k * OUTD + o];
        out[i] = a;
    }
}

extern "C" void kernel_launch(void* const* d_in, const int* in_sizes, int n_in,
                              void* d_out, int out_size, void* d_ws, size_t ws_size,
                              hipStream_t stream) {
    const float* x    = (const float*)d_in[0];
    const int*  edge  = (const int*)d_in[1];
    const int*  batch = (const int*)d_in[2];
    const float* W1 = (const float*)d_in[3];
    const float* b1 = (const float*)d_in[4];
    const float* W2 = (const float*)d_in[5];
    const float* b2 = (const float*)d_in[6];
    const float* W3 = (const float*)d_in[7];
    const float* b3 = (const float*)d_in[8];
    const float* Wm1 = (const float*)d_in[9];
    const float* bm1 = (const float*)d_in[10];
    const float* Wm2 = (const float*)d_in[11];
    const float* bm2 = (const float*)d_in[12];

    const int N_ = in_sizes[2];           // 100000
    const int E_ = in_sizes[1] / 2;       // 1600000
    const int* src = edge;
    const int* dst = edge + E_;
    const int nbins = (N_ + BINSZ - 1) >> BINSHIFT;   // 196

    // workspace carve (256 B aligned)
    char* w = (char*)d_ws;
    auto alloc = [&](size_t bytes) -> void* {
        void* p = (void*)w;
        w += (bytes + 255) & ~(size_t)255;
        return p;
    };
    float* dinv   = (float*)alloc((size_t)N_ * 4);
    unsigned int* rowinfo = (unsigned int*)alloc((size_t)N_ * 4);
    float* pooled = (float*)alloc((size_t)(NG * 64 + NG) * 4);   // 16640 B
    int*   binCount = (int*)alloc(256 * 4);                      // adjacent to pooled
    float* gcnt   = pooled + NG * 64;
    int*   ssrc   = (int*)alloc((size_t)nbins * BSTRIDE * 4);
    unsigned int* binned = (unsigned int*)alloc((size_t)nbins * BSTRIDE * 4);
    unsigned short* Tb  = (unsigned short*)alloc((size_t)N_ * 64 * 2);
    unsigned short* hBb = (unsigned short*)alloc((size_t)N_ * 64 * 2);
    unsigned short* WT1 = (unsigned short*)alloc((size_t)64 * IND * 2);
    unsigned short* WT2 = (unsigned short*)alloc((size_t)64 * HD * 2);
    unsigned short* WT3 = (unsigned short*)alloc((size_t)64 * HD * 2);

    // zero pooled + gcnt + binCount in one shot (contiguous carve)
    hipMemsetAsync(pooled, 0, (size_t)(NG * 64 + NG) * 4 + 256 * 4 + 256, stream);

    // ---- CSR build: 2 dispatches, 1024-thread blocks ----
    binP_kernel<<<PB, 1024, 0, stream>>>(src, dst, binCount, binned, E_, nbins);
    binHD_kernel<<<nbins, 1024, 0, stream>>>(binned, binCount, dinv, rowinfo, ssrc, N_);

    // ---- prep: weight transposes + gcnt (1 dispatch) ----
    prep_kernel<<<64 + 16, 256, 0, stream>>>(W1, W2, W3, WT1, WT2, WT3, batch, gcnt, N_);

    const int mmblk = (N_ + 63) / 64;             // 64 nodes per block (4 waves x 16)
    const int aggblk = (N_ + 7) / 8;              // 4 waves x 2 nodes per block

    // layer 1
    mm_mfma_kernel<IND, false><<<mmblk, 256, 0, stream>>>(x, WT1, dinv, Tb, N_);
    agg_kernel<<<aggblk, 256, 0, stream>>>(Tb, rowinfo, ssrc, dinv, b1, hBb, N_);
    // layer 2
    mm_mfma_kernel<HD, true><<<mmblk, 256, 0, stream>>>(hBb, WT2, dinv, Tb, N_);
    agg_kernel<<<aggblk, 256, 0, stream>>>(Tb, rowinfo, ssrc, dinv, b2, hBb, N_);
    // layer 3
    mm_mfma_kernel<HD, true><<<mmblk, 256, 0, stream>>>(hBb, WT3, dinv, Tb, N_);
    agg_kernel<<<aggblk, 256, 0, stream>>>(Tb, rowinfo, ssrc, dinv, b3, hBb, N_);

    // pool + head
    pool_kernel<<<256, 256, 0, stream>>>(hBb, batch, pooled, N_);
    head_kernel<<<1, 256, 0, stream>>>(pooled, gcnt, Wm1, bm1, Wm2, bm2, (float*)d_out);
}